// Round 14
// baseline (83.589 us; speedup 1.0000x reference)
//
#include <hip/hip_runtime.h>
#include <hip/hip_cooperative_groups.h>
#include <math.h>

namespace cg = cooperative_groups;

// Problem constants (B=16, T=2048, D=1024, K=8)
#define BT     32768   // B*T rows
#define DD     1024    // D
#define DV     256     // float4 per row (D/4)
#define KC     8       // clusters
// Fused (cooperative) config: 4 blocks/CU x 256 CUs
#define NBLKF  1024
#define RPBF   32      // rows per block = BT/NBLKF
// Fallback (round-7 proven, 83.3us) config
#define NPART  512
#define G3     2048
#define RPB3   16

typedef float fv4 __attribute__((ext_vector_type(4)));

// ===========================================================================
// FUSED cooperative kernel. Round-13 result: 1 dispatch == 3 dispatches
// (83.4 vs 83.3us) -> dispatch overhead theory dead; decomposition says the
// two grid.sync()s cost ~25us total. THIS ROUND: replace sync #2 with a
// release/acquire done-counter (fold blocks release-increment after writing
// colsum; everyone acquire-spins to 256). Sync #1 stays (it orders the
// done=0 reset). done zeroed by block 0 before sync #1 -> deterministic.
// ===========================================================================
__global__ __launch_bounds__(256, 4) void fused(
        const float* __restrict__ x,
        const float* __restrict__ mus,
        const float* __restrict__ wmix,
        const float* __restrict__ log_tau,
        const float* __restrict__ log_blend,
        float* __restrict__ out,
        float* __restrict__ part,
        float* __restrict__ colsum,
        unsigned* __restrict__ done) {
    const int tid = threadIdx.x;
    const int bid = blockIdx.x;
    cg::grid_group grid = cg::this_grid();

    const fv4* xv = (const fv4*)x;
    const long row0 = (long)bid * RPBF;

    __shared__ fv4 red[256];
    __shared__ float l2[KC][4];

    // ---- reset the release counter (ordered before sync #1) --------------
    if (bid == 0 && tid == 0)
        __hip_atomic_store(done, 0u, __ATOMIC_RELAXED, __HIP_MEMORY_SCOPE_AGENT);

    // ---- P1: column partial sums, ILP-8 ----------------------------------
    {
        fv4 acc = (fv4)(0.f);
        for (int r = 0; r < RPBF; r += 8) {
            fv4 v[8];
#pragma unroll
            for (int i = 0; i < 8; ++i)
                v[i] = xv[(row0 + r + i) * DV + tid];
#pragma unroll
            for (int i = 0; i < 8; ++i) acc += v[i];
        }
        ((fv4*)part)[(long)bid * DV + tid] = acc;
    }
    grid.sync();   // sync #1: all partials visible; done=0 visible

    // ---- P2a: blocks 0..255 fold fv4-column bid over 1024 partial rows ---
    if (bid < DV) {
        fv4 a = (fv4)(0.f);
#pragma unroll
        for (int j = 0; j < NBLKF / 256; ++j)
            a += ((const fv4*)part)[(long)(tid + j * 256) * DV + bid];
        red[tid] = a;
        __syncthreads();
#pragma unroll
        for (int s = 128; s > 0; s >>= 1) {
            if (tid < s) red[tid] += red[tid + s];
            __syncthreads();
        }
        if (tid == 0) {
            ((fv4*)colsum)[bid] = red[0];
            // release: colsum[bid] ordered before the increment
            __hip_atomic_fetch_add(done, 1u, __ATOMIC_RELEASE,
                                   __HIP_MEMORY_SCOPE_AGENT);
        }
    }

    // ---- sync #2 replacement: acquire-spin until all 256 columns done ----
    if (tid == 0) {
        while (__hip_atomic_load(done, __ATOMIC_ACQUIRE,
                                 __HIP_MEMORY_SCOPE_AGENT) < (unsigned)DV)
            __builtin_amdgcn_s_sleep(2);
    }
    __syncthreads();

    // ---- mu loaded once: used by P2b distance AND P3 famil ---------------
    float mu[KC][4];
#pragma unroll
    for (int k = 0; k < KC; ++k) {
        fv4 m4 = ((const fv4*)mus)[k * DV + tid];
        mu[k][0] = m4.x; mu[k][1] = m4.y; mu[k][2] = m4.z; mu[k][3] = m4.w;
    }

    // ---- P2b: responsibilities (redundant per block) ----------------------
    float rk[KC];
    {
        const float inv_bt = 1.0f / (float)BT;
        fv4 s = ((const fv4*)colsum)[tid];
        float m[4] = { s.x * inv_bt, s.y * inv_bt, s.z * inv_bt, s.w * inv_bt };
        float prt[KC];
#pragma unroll
        for (int k = 0; k < KC; ++k) {
            float d0 = m[0] - mu[k][0], d1 = m[1] - mu[k][1];
            float d2 = m[2] - mu[k][2], d3 = m[3] - mu[k][3];
            prt[k] = d0 * d0 + d1 * d1 + d2 * d2 + d3 * d3;
        }
        const int lane = tid & 63, wv = tid >> 6;
#pragma unroll
        for (int k = 0; k < KC; ++k) {
            float v = prt[k];
#pragma unroll
            for (int off = 32; off > 0; off >>= 1) v += __shfl_down(v, off, 64);
            if (lane == 0) l2[k][wv] = v;
        }
        __syncthreads();
        float logits[KC], mx = -1e30f;
#pragma unroll
        for (int k = 0; k < KC; ++k) {
            float tot = l2[k][0] + l2[k][1] + l2[k][2] + l2[k][3];
            float dist = sqrtf(tot * (1.0f / (float)DD));
            logits[k] = logf(wmix[k]) - dist;
            mx = fmaxf(mx, logits[k]);
        }
        float se = 0.f, e[KC];
#pragma unroll
        for (int k = 0; k < KC; ++k) { e[k] = expf(logits[k] - mx); se += e[k]; }
        float is = 1.f / se;
#pragma unroll
        for (int k = 0; k < KC; ++k) rk[k] = e[k] * is;
    }

    // ---- P3: famil/GELU, ILP-8, NT store ----------------------------------
    {
        const float LOG2E = 1.44269504f;
        fv4 lt = ((const fv4*)log_tau)[tid];
        fv4 lb = ((const fv4*)log_blend)[tid];
        float tl[4], al[4];
        tl[0] = __builtin_amdgcn_exp2f(lt.x * LOG2E) * LOG2E;
        tl[1] = __builtin_amdgcn_exp2f(lt.y * LOG2E) * LOG2E;
        tl[2] = __builtin_amdgcn_exp2f(lt.z * LOG2E) * LOG2E;
        tl[3] = __builtin_amdgcn_exp2f(lt.w * LOG2E) * LOG2E;
        al[0] = 1.f / (1.f + __builtin_amdgcn_exp2f(-lb.x * LOG2E));
        al[1] = 1.f / (1.f + __builtin_amdgcn_exp2f(-lb.y * LOG2E));
        al[2] = 1.f / (1.f + __builtin_amdgcn_exp2f(-lb.z * LOG2E));
        al[3] = 1.f / (1.f + __builtin_amdgcn_exp2f(-lb.w * LOG2E));

        fv4* ov = (fv4*)out;
        for (int rr = 0; rr < RPBF; rr += 8) {
            fv4 v[8];
#pragma unroll
            for (int i = 0; i < 8; ++i)
                v[i] = xv[(row0 + rr + i) * DV + tid];
#pragma unroll
            for (int i = 0; i < 8; ++i) {
                float xin[4] = { v[i].x, v[i].y, v[i].z, v[i].w };
                float o[4];
#pragma unroll
                for (int e = 0; e < 4; ++e) {
                    float xe = xin[e];
                    float fam = 0.f;
#pragma unroll
                    for (int k = 0; k < KC; ++k)
                        fam += rk[k] * __builtin_amdgcn_exp2f(-tl[e] * fabsf(xe - mu[k][e]));
                    float y = xe * (1.f - al[e] * fam);
                    float z = 0.79788456f * (y + 0.044715f * y * y * y);
                    float e2 = __builtin_amdgcn_exp2f(2.88539008f * z);
                    float th = 1.f - 2.f * __builtin_amdgcn_rcpf(e2 + 1.f);
                    o[e] = 0.5f * y * (1.f + th);
                }
                fv4 res; res.x = o[0]; res.y = o[1]; res.z = o[2]; res.w = o[3];
                __builtin_nontemporal_store(res, &ov[(row0 + rr + i) * DV + tid]);
            }
        }
    }
}

// ===========================================================================
// FALLBACK path — byte-identical to round 7's proven 83.3us structure.
// ===========================================================================
__global__ __launch_bounds__(256) void kA_partial(const float* __restrict__ x,
                                                  float* __restrict__ part,
                                                  int rows_per_blk) {
    const int tid = threadIdx.x;
    const fv4* xv = (const fv4*)x;
    const long row0 = (long)blockIdx.x * rows_per_blk;
    fv4 acc = (fv4)(0.f);
    for (int r = 0; r < rows_per_blk; r += 8) {
        fv4 v[8];
#pragma unroll
        for (int i = 0; i < 8; ++i)
            v[i] = xv[(row0 + r + i) * DV + tid];
#pragma unroll
        for (int i = 0; i < 8; ++i) acc += v[i];
    }
    ((fv4*)part)[(long)blockIdx.x * DV + tid] = acc;
}

__global__ __launch_bounds__(256) void kB_fold(const float* __restrict__ part,
                                               float* __restrict__ colsum) {
    const int tid = threadIdx.x;
    const int b = blockIdx.x;
    __shared__ fv4 red[256];
    fv4 a = ((const fv4*)part)[(long)tid * DV + b] +
            ((const fv4*)part)[(long)(tid + 256) * DV + b];
    red[tid] = a;
    __syncthreads();
#pragma unroll
    for (int s = 128; s > 0; s >>= 1) {
        if (tid < s) red[tid] += red[tid + s];
        __syncthreads();
    }
    if (tid == 0) ((fv4*)colsum)[b] = red[0];
}

__global__ __launch_bounds__(256) void kC_main(const float* __restrict__ x,
                                               const float* __restrict__ mus,
                                               const float* __restrict__ wmix,
                                               const float* __restrict__ log_tau,
                                               const float* __restrict__ log_blend,
                                               const float* __restrict__ colsum,
                                               float* __restrict__ out) {
    const int tid = threadIdx.x;
    const long row0 = (long)blockIdx.x * RPB3;
    const fv4* xv = (const fv4*)x;

    float rk[KC];
    {
        const float inv_bt = 1.0f / (float)BT;
        fv4 s = ((const fv4*)colsum)[tid];
        float m[4] = { s.x * inv_bt, s.y * inv_bt, s.z * inv_bt, s.w * inv_bt };
        float prt[KC];
#pragma unroll
        for (int k = 0; k < KC; ++k) {
            fv4 mu = ((const fv4*)mus)[k * DV + tid];
            float d0 = m[0] - mu.x, d1 = m[1] - mu.y;
            float d2 = m[2] - mu.z, d3 = m[3] - mu.w;
            prt[k] = d0 * d0 + d1 * d1 + d2 * d2 + d3 * d3;
        }
        __shared__ float l2[KC][4];
        const int lane = tid & 63, wv = tid >> 6;
#pragma unroll
        for (int k = 0; k < KC; ++k) {
            float v = prt[k];
#pragma unroll
            for (int off = 32; off > 0; off >>= 1) v += __shfl_down(v, off, 64);
            if (lane == 0) l2[k][wv] = v;
        }
        __syncthreads();
        float logits[KC], mx = -1e30f;
#pragma unroll
        for (int k = 0; k < KC; ++k) {
            float tot = l2[k][0] + l2[k][1] + l2[k][2] + l2[k][3];
            float dist = sqrtf(tot * (1.0f / (float)DD));
            logits[k] = logf(wmix[k]) - dist;
            mx = fmaxf(mx, logits[k]);
        }
        float se = 0.f, e[KC];
#pragma unroll
        for (int k = 0; k < KC; ++k) { e[k] = expf(logits[k] - mx); se += e[k]; }
        float is = 1.f / se;
#pragma unroll
        for (int k = 0; k < KC; ++k) rk[k] = e[k] * is;
    }

    const float LOG2E = 1.44269504f;
    fv4 lt = ((const fv4*)log_tau)[tid];
    fv4 lb = ((const fv4*)log_blend)[tid];
    float tl[4], al[4];
    tl[0] = __builtin_amdgcn_exp2f(lt.x * LOG2E) * LOG2E;
    tl[1] = __builtin_amdgcn_exp2f(lt.y * LOG2E) * LOG2E;
    tl[2] = __builtin_amdgcn_exp2f(lt.z * LOG2E) * LOG2E;
    tl[3] = __builtin_amdgcn_exp2f(lt.w * LOG2E) * LOG2E;
    al[0] = 1.f / (1.f + __builtin_amdgcn_exp2f(-lb.x * LOG2E));
    al[1] = 1.f / (1.f + __builtin_amdgcn_exp2f(-lb.y * LOG2E));
    al[2] = 1.f / (1.f + __builtin_amdgcn_exp2f(-lb.z * LOG2E));
    al[3] = 1.f / (1.f + __builtin_amdgcn_exp2f(-lb.w * LOG2E));

    float mu[KC][4];
#pragma unroll
    for (int k = 0; k < KC; ++k) {
        fv4 m4 = ((const fv4*)mus)[k * DV + tid];
        mu[k][0] = m4.x; mu[k][1] = m4.y; mu[k][2] = m4.z; mu[k][3] = m4.w;
    }

    fv4* ov = (fv4*)out;
    for (int rr = 0; rr < RPB3; rr += 4) {
        fv4 v[4];
#pragma unroll
        for (int i = 0; i < 4; ++i)
            v[i] = xv[(row0 + rr + i) * DV + tid];
#pragma unroll
        for (int i = 0; i < 4; ++i) {
            float xin[4] = { v[i].x, v[i].y, v[i].z, v[i].w };
            float o[4];
#pragma unroll
            for (int e = 0; e < 4; ++e) {
                float xe = xin[e];
                float fam = 0.f;
#pragma unroll
                for (int k = 0; k < KC; ++k)
                    fam += rk[k] * __builtin_amdgcn_exp2f(-tl[e] * fabsf(xe - mu[k][e]));
                float y = xe * (1.f - al[e] * fam);
                float z = 0.79788456f * (y + 0.044715f * y * y * y);
                float e2 = __builtin_amdgcn_exp2f(2.88539008f * z);
                float th = 1.f - 2.f * __builtin_amdgcn_rcpf(e2 + 1.f);
                o[e] = 0.5f * y * (1.f + th);
            }
            fv4 res; res.x = o[0]; res.y = o[1]; res.z = o[2]; res.w = o[3];
            __builtin_nontemporal_store(res, &ov[(row0 + rr + i) * DV + tid]);
        }
    }
}

extern "C" void kernel_launch(void* const* d_in, const int* in_sizes, int n_in,
                              void* d_out, int out_size, void* d_ws, size_t ws_size,
                              hipStream_t stream) {
    const float* x         = (const float*)d_in[0];
    const float* mus       = (const float*)d_in[1];
    const float* wmix      = (const float*)d_in[2];
    const float* log_tau   = (const float*)d_in[3];
    const float* log_blend = (const float*)d_in[4];
    float* out = (float*)d_out;

    // Capacity check (host-side query: capture-safe, deterministic).
    int blocksPerCU = 0;
    hipError_t qerr = hipOccupancyMaxActiveBlocksPerMultiprocessor(
        &blocksPerCU, (const void*)fused, 256, 0);
    const bool coop_ok = (qerr == hipSuccess) && (blocksPerCU * 256 >= NBLKF);

    if (coop_ok) {
        float* part     = (float*)d_ws;              // NBLKF*DD floats (4 MB)
        float* colsum   = part + (long)NBLKF * DD;   // DD floats (4 KB)
        unsigned* done  = (unsigned*)(colsum + DD);  // 1 u32
        void* args[] = { (void*)&x, (void*)&mus, (void*)&wmix, (void*)&log_tau,
                         (void*)&log_blend, (void*)&out, (void*)&part,
                         (void*)&colsum, (void*)&done };
        (void)hipLaunchCooperativeKernel((const void*)fused, dim3(NBLKF),
                                         dim3(256), args, 0, stream);
    } else {
        float* part   = (float*)d_ws;              // NPART*DD floats (2 MB)
        float* colsum = part + (long)NPART * DD;   // DD floats (4 KB)
        kA_partial<<<NPART, 256, 0, stream>>>(x, part, BT / NPART);
        kB_fold<<<DV, 256, 0, stream>>>(part, colsum);
        kC_main<<<G3, 256, 0, stream>>>(x, mus, wmix, log_tau, log_blend,
                                        colsum, out);
    }
}